// Round 2
// baseline (282.258 us; speedup 1.0000x reference)
//
#include <hip/hip_runtime.h>

#define NCLS 19
#define HW (512 * 512)
#define NPIX (8 * HW)

__global__ __launch_bounds__(256) void lms_main_kernel(
    const float* __restrict__ logits, const int* __restrict__ labels,
    float* __restrict__ ws) {
  const float COEFF = 1.0f / 18.0f;  // 1/(C-1)
  const float LAM_HALF = 0.15f;      // 0.3 / 2

  int t = blockIdx.x * blockDim.x + threadIdx.x;  // one thread = 2 pixels
  long p = (long)t * 2;

  float loss = 0.0f;
  float cnt = 0.0f;

  if (p < NPIX) {
    int n = (int)(p / HW);          // HW is 2^18 -> shifts
    int hw = (int)(p % HW);
    const float* base = logits + (size_t)n * NCLS * HW + hw;

    int2 lb2 = *(const int2*)(labels + p);

    // 19 channels x 2 pixels, 8B coalesced loads, kept in registers
    float2 x[NCLS];
#pragma unroll
    for (int c = 0; c < NCLS; ++c)
      x[c] = *(const float2*)(base + (size_t)c * HW);

#pragma unroll
    for (int j = 0; j < 2; ++j) {
      int lb = j ? lb2.y : lb2.x;
      bool valid = (lb != 255);
      int l = valid ? lb : 0;

      // pass 1: max (fully unrolled, named-member access only)
      float M = j ? x[0].y : x[0].x;
#pragma unroll
      for (int c = 1; c < NCLS; ++c) {
        float xv = j ? x[c].y : x[c].x;
        M = fmaxf(M, xv);
      }

      // pass 2: fused sums; x_l extracted via unrolled select chain
      float s_all = 0.0f;  // sum exp(x-M)
      float T = 0.0f;      // sum exp(x-M)*x
      float S = 0.0f;      // sum x
      float x_l = 0.0f;
#pragma unroll
      for (int c = 0; c < NCLS; ++c) {
        float xv = j ? x[c].y : x[c].x;
        float e = __expf(xv - M);
        s_all += e;
        T += e * xv;
        S += xv;
        x_l = (c == l) ? xv : x_l;
      }

      float e_l = __expf(x_l - M);
      float s_m = s_all - e_l;          // masked partition (exact: exp(NEG)=0)
      float T_m = T - e_l * x_l;
      float S_m = S - x_l;

      // margin = sum_{c!=l} q_c*x_c - coeff*sum_{c!=l} x_c   (lse_m cancels)
      float margin = T_m / s_m - COEFF * S_m;
      float ce = M + __logf(s_all) - x_l;

      float pixel_loss = ce + LAM_HALF * margin;
      loss += valid ? pixel_loss : 0.0f;
      cnt += valid ? 1.0f : 0.0f;
    }
  }

  // 64-lane wave shuffle reduction
#pragma unroll
  for (int off = 32; off > 0; off >>= 1) {
    loss += __shfl_down(loss, off, 64);
    cnt += __shfl_down(cnt, off, 64);
  }

  __shared__ float sl[4], sc[4];
  int wave = threadIdx.x >> 6;
  int lane = threadIdx.x & 63;
  if (lane == 0) {
    sl[wave] = loss;
    sc[wave] = cnt;
  }
  __syncthreads();
  if (threadIdx.x == 0) {
    atomicAdd(ws, sl[0] + sl[1] + sl[2] + sl[3]);
    atomicAdd(ws + 1, sc[0] + sc[1] + sc[2] + sc[3]);
  }
}

__global__ void lms_final_kernel(const float* __restrict__ ws,
                                 float* __restrict__ out) {
  out[0] = ws[0] / ws[1];
}

extern "C" void kernel_launch(void* const* d_in, const int* in_sizes, int n_in,
                              void* d_out, int out_size, void* d_ws, size_t ws_size,
                              hipStream_t stream) {
  const float* logits = (const float*)d_in[0];
  const int* labels = (const int*)d_in[1];
  float* out = (float*)d_out;
  float* ws = (float*)d_ws;

  hipMemsetAsync(ws, 0, 2 * sizeof(float), stream);

  int threads = 256;
  int pairs = NPIX / 2;                          // 1,048,576 threads
  int blocks = (pairs + threads - 1) / threads;  // 4096 blocks
  lms_main_kernel<<<blocks, threads, 0, stream>>>(logits, labels, ws);
  lms_final_kernel<<<1, 1, 0, stream>>>(ws, out);
}

// Round 3
// 227.971 us; speedup vs baseline: 1.2381x; 1.2381x over previous
//
#include <hip/hip_runtime.h>

#define NCLS 19
#define HW (512 * 512)
#define NPIX (8 * HW)
#define NBLK 2048   // NPIX/4/256

__global__ __launch_bounds__(256) void lms_main_kernel(
    const float* __restrict__ logits, const int* __restrict__ labels,
    float* __restrict__ partials) {
  const float COEFF = 1.0f / 18.0f;  // 1/(C-1)
  const float LAM_HALF = 0.15f;      // 0.3 / 2

  int t = blockIdx.x * blockDim.x + threadIdx.x;  // one thread = 4 pixels
  long p = (long)t * 4;

  int n = (int)(p >> 18);           // p / HW
  int hw = (int)(p & (HW - 1));     // p % HW
  const float* base = logits + (size_t)n * NCLS * HW + hw;

  // labels for the quad
  int4 lb4 = *(const int4*)(labels + p);
  int l0 = (lb4.x != 255) ? lb4.x : 0;
  int l1 = (lb4.y != 255) ? lb4.y : 0;
  int l2 = (lb4.z != 255) ? lb4.z : 0;
  int l3 = (lb4.w != 255) ? lb4.w : 0;

  // gather the label-class logit per pixel (L3-resident, issued early)
  float xl0 = base[(size_t)l0 * HW + 0];
  float xl1 = base[(size_t)l1 * HW + 1];
  float xl2 = base[(size_t)l2 * HW + 2];
  float xl3 = base[(size_t)l3 * HW + 3];

  // fused single pass: each loaded float4 is consumed immediately (single use)
  float s0 = 0.f, s1 = 0.f, s2 = 0.f, s3 = 0.f;   // sum exp(x)
  float T0 = 0.f, T1 = 0.f, T2 = 0.f, T3 = 0.f;   // sum exp(x)*x
  float S0 = 0.f, S1 = 0.f, S2 = 0.f, S3 = 0.f;   // sum x
#pragma unroll
  for (int c = 0; c < NCLS; ++c) {
    float4 v = *(const float4*)(base + (size_t)c * HW);
    float e;
    e = __expf(v.x); s0 += e; T0 += e * v.x; S0 += v.x;
    e = __expf(v.y); s1 += e; T1 += e * v.y; S1 += v.y;
    e = __expf(v.z); s2 += e; T2 += e * v.z; S2 += v.z;
    e = __expf(v.w); s3 += e; T3 += e * v.w; S3 += v.w;
  }

  float loss = 0.f, cnt = 0.f;
#define PIXEL(s, T, S, xl, lbv)                                   \
  {                                                               \
    float el = __expf(xl);                                        \
    float sm = s - el;                                            \
    float margin = (T - el * xl) / sm - COEFF * (S - xl);         \
    float ce = __logf(s) - xl;                                    \
    bool valid = (lbv != 255);                                    \
    loss += valid ? (ce + LAM_HALF * margin) : 0.f;               \
    cnt += valid ? 1.f : 0.f;                                     \
  }
  PIXEL(s0, T0, S0, xl0, lb4.x)
  PIXEL(s1, T1, S1, xl1, lb4.y)
  PIXEL(s2, T2, S2, xl2, lb4.z)
  PIXEL(s3, T3, S3, xl3, lb4.w)
#undef PIXEL

  // 64-lane wave shuffle reduction
#pragma unroll
  for (int off = 32; off > 0; off >>= 1) {
    loss += __shfl_down(loss, off, 64);
    cnt += __shfl_down(cnt, off, 64);
  }

  __shared__ float sl[4], sc[4];
  int wave = threadIdx.x >> 6;
  int lane = threadIdx.x & 63;
  if (lane == 0) {
    sl[wave] = loss;
    sc[wave] = cnt;
  }
  __syncthreads();
  if (threadIdx.x == 0) {
    partials[2 * blockIdx.x] = sl[0] + sl[1] + sl[2] + sl[3];
    partials[2 * blockIdx.x + 1] = sc[0] + sc[1] + sc[2] + sc[3];
  }
}

__global__ __launch_bounds__(1024) void lms_final_kernel(
    const float* __restrict__ partials, float* __restrict__ out) {
  // 2048 partial pairs, 1024 threads x 2 pairs each
  int t = threadIdx.x;
  float loss = partials[2 * t] + partials[2 * (t + 1024)];
  float cnt = partials[2 * t + 1] + partials[2 * (t + 1024) + 1];
#pragma unroll
  for (int off = 32; off > 0; off >>= 1) {
    loss += __shfl_down(loss, off, 64);
    cnt += __shfl_down(cnt, off, 64);
  }
  __shared__ float sl[16], sc[16];
  int wave = t >> 6;
  int lane = t & 63;
  if (lane == 0) {
    sl[wave] = loss;
    sc[wave] = cnt;
  }
  __syncthreads();
  if (t == 0) {
    float L = 0.f, C = 0.f;
#pragma unroll
    for (int w = 0; w < 16; ++w) {
      L += sl[w];
      C += sc[w];
    }
    out[0] = L / C;
  }
}

extern "C" void kernel_launch(void* const* d_in, const int* in_sizes, int n_in,
                              void* d_out, int out_size, void* d_ws, size_t ws_size,
                              hipStream_t stream) {
  const float* logits = (const float*)d_in[0];
  const int* labels = (const int*)d_in[1];
  float* out = (float*)d_out;
  float* partials = (float*)d_ws;  // 2048 blocks x {loss, cnt} = 16 KB

  lms_main_kernel<<<NBLK, 256, 0, stream>>>(logits, labels, partials);
  lms_final_kernel<<<1, 1024, 0, stream>>>(partials, out);
}

// Round 4
// 225.932 us; speedup vs baseline: 1.2493x; 1.0090x over previous
//
#include <hip/hip_runtime.h>

#define NCLS 19
#define HW (512 * 512)
#define NPIX (8 * HW)
#define NBLK 2048  // NPIX/4/256

__global__ __launch_bounds__(256, 1) void lms_main_kernel(
    const float* __restrict__ logits, const int* __restrict__ labels,
    float* __restrict__ partials) {
  const float COEFF = 1.0f / 18.0f;  // 1/(C-1)
  const float LAM_HALF = 0.15f;      // 0.3 / 2

  int t = blockIdx.x * blockDim.x + threadIdx.x;  // one thread = 4 pixels
  long p = (long)t * 4;

  int n = (int)(p >> 18);        // p / HW
  int hw = (int)(p & (HW - 1));  // p % HW
  const float* base = logits + (size_t)n * NCLS * HW + hw;

  int4 lb4 = *(const int4*)(labels + p);
  int l0 = (lb4.x != 255) ? lb4.x : 0;
  int l1 = (lb4.y != 255) ? lb4.y : 0;
  int l2 = (lb4.z != 255) ? lb4.z : 0;
  int l3 = (lb4.w != 255) ? lb4.w : 0;

  // ---- phase 1: issue ALL loads before any consumption (deep MLP) ----
  float4 x[NCLS];
#pragma unroll
  for (int c = 0; c < NCLS; ++c)
    x[c] = *(const float4*)(base + (size_t)c * HW);

  // label-class logit gathers (L2/L3-resident; needed only in epilogue)
  float xl0 = base[(size_t)l0 * HW + 0];
  float xl1 = base[(size_t)l1 * HW + 1];
  float xl2 = base[(size_t)l2 * HW + 2];
  float xl3 = base[(size_t)l3 * HW + 3];

  // ---- phase 2: consume (constant indices only; fully unrolled) ----
  float s0 = 0.f, s1 = 0.f, s2 = 0.f, s3 = 0.f;  // sum exp(x)
  float T0 = 0.f, T1 = 0.f, T2 = 0.f, T3 = 0.f;  // sum exp(x)*x
  float S0 = 0.f, S1 = 0.f, S2 = 0.f, S3 = 0.f;  // sum x
#pragma unroll
  for (int c = 0; c < NCLS; ++c) {
    float e;
    e = __expf(x[c].x); s0 += e; T0 += e * x[c].x; S0 += x[c].x;
    e = __expf(x[c].y); s1 += e; T1 += e * x[c].y; S1 += x[c].y;
    e = __expf(x[c].z); s2 += e; T2 += e * x[c].z; S2 += x[c].z;
    e = __expf(x[c].w); s3 += e; T3 += e * x[c].w; S3 += x[c].w;
  }

  float loss = 0.f, cnt = 0.f;
#define PIXEL(s, T, S, xl, lbv)                              \
  {                                                          \
    float el = __expf(xl);                                   \
    float sm = s - el;                                       \
    float margin = (T - el * xl) / sm - COEFF * (S - xl);    \
    float ce = __logf(s) - xl;                               \
    bool valid = (lbv != 255);                               \
    loss += valid ? (ce + LAM_HALF * margin) : 0.f;          \
    cnt += valid ? 1.f : 0.f;                                \
  }
  PIXEL(s0, T0, S0, xl0, lb4.x)
  PIXEL(s1, T1, S1, xl1, lb4.y)
  PIXEL(s2, T2, S2, xl2, lb4.z)
  PIXEL(s3, T3, S3, xl3, lb4.w)
#undef PIXEL

  // 64-lane wave shuffle reduction
#pragma unroll
  for (int off = 32; off > 0; off >>= 1) {
    loss += __shfl_down(loss, off, 64);
    cnt += __shfl_down(cnt, off, 64);
  }

  __shared__ float sl[4], sc[4];
  int wave = threadIdx.x >> 6;
  int lane = threadIdx.x & 63;
  if (lane == 0) {
    sl[wave] = loss;
    sc[wave] = cnt;
  }
  __syncthreads();
  if (threadIdx.x == 0) {
    partials[2 * blockIdx.x] = sl[0] + sl[1] + sl[2] + sl[3];
    partials[2 * blockIdx.x + 1] = sc[0] + sc[1] + sc[2] + sc[3];
  }
}

__global__ __launch_bounds__(1024) void lms_final_kernel(
    const float* __restrict__ partials, float* __restrict__ out) {
  int t = threadIdx.x;
  float loss = partials[2 * t] + partials[2 * (t + 1024)];
  float cnt = partials[2 * t + 1] + partials[2 * (t + 1024) + 1];
#pragma unroll
  for (int off = 32; off > 0; off >>= 1) {
    loss += __shfl_down(loss, off, 64);
    cnt += __shfl_down(cnt, off, 64);
  }
  __shared__ float sl[16], sc[16];
  int wave = t >> 6;
  int lane = t & 63;
  if (lane == 0) {
    sl[wave] = loss;
    sc[wave] = cnt;
  }
  __syncthreads();
  if (t == 0) {
    float L = 0.f, C = 0.f;
#pragma unroll
    for (int w = 0; w < 16; ++w) {
      L += sl[w];
      C += sc[w];
    }
    out[0] = L / C;
  }
}

extern "C" void kernel_launch(void* const* d_in, const int* in_sizes, int n_in,
                              void* d_out, int out_size, void* d_ws, size_t ws_size,
                              hipStream_t stream) {
  const float* logits = (const float*)d_in[0];
  const int* labels = (const int*)d_in[1];
  float* out = (float*)d_out;
  float* partials = (float*)d_ws;  // 2048 x {loss, cnt} = 16 KB

  lms_main_kernel<<<NBLK, 256, 0, stream>>>(logits, labels, partials);
  lms_final_kernel<<<1, 1024, 0, stream>>>(partials, out);
}

// Round 5
// 222.407 us; speedup vs baseline: 1.2691x; 1.0158x over previous
//
#include <hip/hip_runtime.h>

#define NCLS 19
#define HW (512 * 512)
#define NPIX (8 * HW)
#define TILE 512                  // pixels per block (512 blocks/image, never straddles)
#define NBLK (NPIX / TILE)        // 4096 blocks
#define CHUNKS (NCLS * TILE / 4)  // 16B chunks staged per block = 2432

__global__ __launch_bounds__(256) void lms_main_kernel(
    const float* __restrict__ logits, const int* __restrict__ labels,
    float* __restrict__ partials) {
  const float COEFF = 1.0f / 18.0f;  // 1/(C-1)
  const float LAM_HALF = 0.15f;      // 0.3 / 2

  __shared__ float tile[NCLS * TILE];  // 38912 B -> 4 blocks/CU

  const int t = threadIdx.x;
  const long pixel0 = (long)blockIdx.x * TILE;
  const int n = (int)(pixel0 >> 18);        // image
  const int hw0 = (int)(pixel0 & (HW - 1)); // pixel offset within image
  const float* gbase = logits + (size_t)n * NCLS * HW + hw0;

  // ---- stage 19 x 512 floats via async global->LDS DMA, 16B chunks ----
  // LDS layout dense row-major (row = channel, 2048 B/row); flat chunk index f
  // gives laddr = f*16 (linear in f => wave lanes are base + lane*16: legal).
#pragma unroll
  for (int f = t; f < CHUNKS; f += 256) {
    int r = f >> 7;     // channel row (f / 128)
    int col = f & 127;  // 16B chunk within row
    const float* g = gbase + (size_t)r * HW + col * 4;
    const __attribute__((address_space(1))) float* g1 =
        (const __attribute__((address_space(1))) float*)(uintptr_t)g;
    __attribute__((address_space(3))) float* l3 =
        (__attribute__((address_space(3))) float*)(uintptr_t)(&tile[f * 4]);
    __builtin_amdgcn_global_load_lds(g1, l3, 16, 0, 0);
  }

  // labels for this thread's two pixels (coalesced 8B)
  int2 lb2 = *(const int2*)(labels + pixel0 + 2 * t);
  int l0 = (lb2.x != 255) ? lb2.x : 0;
  int l1 = (lb2.y != 255) ? lb2.y : 0;

  __syncthreads();  // drains vmcnt incl. global_load_lds (m97 semantics)

  // ---- compute: 2 pixels/thread from LDS (ds_read_b64, 2-way = free) ----
  float s0 = 0.f, T0 = 0.f, S0 = 0.f;
  float s1 = 0.f, T1 = 0.f, S1 = 0.f;
#pragma unroll
  for (int c = 0; c < NCLS; ++c) {
    float2 v = *(const float2*)&tile[c * TILE + 2 * t];
    float e;
    e = __expf(v.x); s0 += e; T0 += e * v.x; S0 += v.x;
    e = __expf(v.y); s1 += e; T1 += e * v.y; S1 += v.y;
  }
  float xl0 = tile[l0 * TILE + 2 * t];
  float xl1 = tile[l1 * TILE + 2 * t + 1];

  float loss = 0.f, cnt = 0.f;
#define PIXEL(s, T, S, xl, lbv)                           \
  {                                                       \
    float el = __expf(xl);                                \
    float sm = s - el;                                    \
    float margin = (T - el * xl) / sm - COEFF * (S - xl); \
    float ce = __logf(s) - xl;                            \
    bool valid = (lbv != 255);                            \
    loss += valid ? (ce + LAM_HALF * margin) : 0.f;       \
    cnt += valid ? 1.f : 0.f;                             \
  }
  PIXEL(s0, T0, S0, xl0, lb2.x)
  PIXEL(s1, T1, S1, xl1, lb2.y)
#undef PIXEL

  // ---- wave (64) shuffle reduction, then block, then per-block partials ----
#pragma unroll
  for (int off = 32; off > 0; off >>= 1) {
    loss += __shfl_down(loss, off, 64);
    cnt += __shfl_down(cnt, off, 64);
  }
  __shared__ float sl[4], sc[4];
  int wave = t >> 6;
  int lane = t & 63;
  if (lane == 0) {
    sl[wave] = loss;
    sc[wave] = cnt;
  }
  __syncthreads();
  if (t == 0) {
    partials[2 * blockIdx.x] = sl[0] + sl[1] + sl[2] + sl[3];
    partials[2 * blockIdx.x + 1] = sc[0] + sc[1] + sc[2] + sc[3];
  }
}

__global__ __launch_bounds__(1024) void lms_final_kernel(
    const float* __restrict__ partials, float* __restrict__ out) {
  // 4096 partial pairs; 1024 threads x 4 pairs each
  int t = threadIdx.x;
  float loss = 0.f, cnt = 0.f;
#pragma unroll
  for (int k = 0; k < 4; ++k) {
    float2 pr = ((const float2*)partials)[t + 1024 * k];
    loss += pr.x;
    cnt += pr.y;
  }
#pragma unroll
  for (int off = 32; off > 0; off >>= 1) {
    loss += __shfl_down(loss, off, 64);
    cnt += __shfl_down(cnt, off, 64);
  }
  __shared__ float sl[16], sc[16];
  int wave = t >> 6;
  int lane = t & 63;
  if (lane == 0) {
    sl[wave] = loss;
    sc[wave] = cnt;
  }
  __syncthreads();
  if (t == 0) {
    float L = 0.f, C = 0.f;
#pragma unroll
    for (int w = 0; w < 16; ++w) {
      L += sl[w];
      C += sc[w];
    }
    out[0] = L / C;
  }
}

extern "C" void kernel_launch(void* const* d_in, const int* in_sizes, int n_in,
                              void* d_out, int out_size, void* d_ws, size_t ws_size,
                              hipStream_t stream) {
  const float* logits = (const float*)d_in[0];
  const int* labels = (const int*)d_in[1];
  float* out = (float*)d_out;
  float* partials = (float*)d_ws;  // 4096 x {loss, cnt} = 32 KB

  lms_main_kernel<<<NBLK, 256, 0, stream>>>(logits, labels, partials);
  lms_final_kernel<<<1, 1024, 0, stream>>>(partials, out);
}